// Round 7
// baseline (230.914 us; speedup 1.0000x reference)
//
#include <hip/hip_runtime.h>
#include <math.h>

#define F_IN 256
#define F_OUT 64
#define NEG_SLOPE 0.01f
#define NB1 256   // coarse-pass blocks

typedef unsigned short ushort8_t __attribute__((ext_vector_type(8)));

__device__ inline unsigned short f2bf(float f) {   // RNE
    unsigned u = __float_as_uint(f);
    u += 0x7FFF + ((u >> 16) & 1);
    return (unsigned short)(u >> 16);
}
__device__ inline float bf2f(unsigned short u) {
    return __uint_as_float(((unsigned)u) << 16);
}

// ---------------------------------------------------------------------------
// K0: transpose W1 (64x256 -> k-major 256x64) and W2 (64x64 -> j-major).
// ---------------------------------------------------------------------------
__global__ void prep_w_kernel(const float* __restrict__ W1,
                              const float* __restrict__ W2,
                              float* __restrict__ w1t,
                              float* __restrict__ w2t)
{
    int idx = blockIdx.x * blockDim.x + threadIdx.x;
    if (idx < F_IN * F_OUT) {
        int k = idx >> 6, f = idx & 63;
        w1t[idx] = W1[f * F_IN + k];
    }
    if (idx < F_OUT * F_OUT) {
        int j = idx >> 6, f = idx & 63;
        w2t[idx] = W2[f * F_OUT + j];
    }
}

// ---------------------------------------------------------------------------
// K1: fused MLP. Block = 256 = 64 nodes (lane) x 4 feature-quarters (wave).
// R6 lesson: per-chunk loads are drained by the NEXT __syncthreads
// (vmcnt(0) before s_barrier) -> 4 exposed HBM stalls/block at only
// 3 waves/SIMD. Fix: ALL 16 dwordx4 loads issued upfront, pinned with
// sched_barrier(0) (R4: allocator sinks unpinned prefetch), under
// __launch_bounds__(256,3) so v[16]+acc fit without spill (~100 VGPR
// < 168 cap). One vmcnt drain per block instead of four.
// ---------------------------------------------------------------------------
__global__ __launch_bounds__(256, 3)
void mlp_kernel(const float* __restrict__ x,
                const float* __restrict__ w1t,
                const float* __restrict__ w2t,
                const float* __restrict__ a,
                unsigned short* __restrict__ hb,
                float* __restrict__ sdst,
                float* __restrict__ ssrc, int N)
{
    __shared__ float xt[64 * 65];   // xt[k][node] per chunk; reused as zh/h
    __shared__ float sred[8][64];
    const int tid = threadIdx.x;
    const int lane = tid & 63;
    const int wq = __builtin_amdgcn_readfirstlane(tid >> 6);
    const int node0 = blockIdx.x * 64;

    // staging: thread t covers row r = t>>2, 64B col-group g = t&3
    const int r = tid >> 2, g = tid & 3;
    const int gnode = min(node0 + r, N - 1);
    const float* __restrict__ xsrc = x + (size_t)gnode * F_IN + g * 16;

    // all 16 16B-loads in flight before any compute
    float4 v[16];
#pragma unroll
    for (int c = 0; c < 16; c++)
        v[c] = *(const float4*)(xsrc + (c >> 2) * 64 + (c & 3) * 4);
    __builtin_amdgcn_sched_barrier(0);   // pin: do not sink loads

    float acc[16];
#pragma unroll
    for (int f = 0; f < 16; f++) acc[f] = 0.f;

#pragma unroll
    for (int kc = 0; kc < 4; kc++) {
        __syncthreads();   // chunk kc=0: drains all loads once; later: cheap
#pragma unroll
        for (int i = 0; i < 4; i++) {
            int k = g * 16 + i * 4;
            float4 vi = v[kc * 4 + i];
            xt[(k + 0) * 65 + r] = vi.x;
            xt[(k + 1) * 65 + r] = vi.y;
            xt[(k + 2) * 65 + r] = vi.z;
            xt[(k + 3) * 65 + r] = vi.w;
        }
        __syncthreads();

        const float* __restrict__ wbase = w1t + (kc * 64) * F_OUT + wq * 16;
#pragma unroll 8
        for (int k = 0; k < 64; k++) {
            float xk = xt[k * 65 + lane];
            const float4* __restrict__ wrow = (const float4*)(wbase + k * F_OUT);
#pragma unroll
            for (int fq = 0; fq < 4; fq++) {
                float4 w = wrow[fq];
                acc[4 * fq + 0] = fmaf(xk, w.x, acc[4 * fq + 0]);
                acc[4 * fq + 1] = fmaf(xk, w.y, acc[4 * fq + 1]);
                acc[4 * fq + 2] = fmaf(xk, w.z, acc[4 * fq + 2]);
                acc[4 * fq + 3] = fmaf(xk, w.w, acc[4 * fq + 3]);
            }
        }
    }
    __syncthreads();   // GEMM1 reads done; reuse xt as zh[node][feat]

#pragma unroll
    for (int f = 0; f < 16; f++)
        xt[lane * 65 + wq * 16 + f] = fmaxf(acc[f], 0.f);
    __syncthreads();

    float hacc[16];
#pragma unroll
    for (int f = 0; f < 16; f++) hacc[f] = 0.f;
    const float* __restrict__ w2p = w2t + wq * 16;
#pragma unroll 8
    for (int j = 0; j < F_OUT; j++) {
        float zj = xt[lane * 65 + j];
        const float4* __restrict__ wrow = (const float4*)(w2p + j * F_OUT);
#pragma unroll
        for (int fq = 0; fq < 4; fq++) {
            float4 w = wrow[fq];
            hacc[4 * fq + 0] = fmaf(zj, w.x, hacc[4 * fq + 0]);
            hacc[4 * fq + 1] = fmaf(zj, w.y, hacc[4 * fq + 1]);
            hacc[4 * fq + 2] = fmaf(zj, w.z, hacc[4 * fq + 2]);
            hacc[4 * fq + 3] = fmaf(zj, w.w, hacc[4 * fq + 3]);
        }
    }
    __syncthreads();

    float sd = 0.f, ss = 0.f;
#pragma unroll
    for (int f = 0; f < 16; f++) {
        float hf = fmaxf(hacc[f], 0.f);
        xt[lane * 65 + wq * 16 + f] = hf;
        sd = fmaf(hf, a[wq * 16 + f], sd);
        ss = fmaf(hf, a[F_OUT + wq * 16 + f], ss);
    }
    sred[wq][lane] = sd;
    sred[4 + wq][lane] = ss;
    __syncthreads();

    if (tid < 64) {
        int node = node0 + lane;
        if (node < N) {
            sdst[node] = sred[0][lane] + sred[1][lane] + sred[2][lane] + sred[3][lane];
            ssrc[node] = sred[4][lane] + sred[5][lane] + sred[6][lane] + sred[7][lane];
        }
    }
#pragma unroll
    for (int i = 0; i < 2; i++) {
        int idx = tid + 256 * i;
        int nn = idx >> 3;
        int c0 = (idx & 7) * 8;
        if (node0 + nn < N) {
            ushort8_t vv;
#pragma unroll
            for (int c = 0; c < 8; c++) vv[c] = f2bf(xt[nn * 65 + c0 + c]);
            *(ushort8_t*)(hb + (size_t)(node0 + nn) * F_OUT + c0) = vv;
        }
    }
}

// ---------------------------------------------------------------------------
// K2: coarse histogram of dst>>8. 1024 threads (R6: 256thr = 1 wave/SIMD,
// LDS-atomic latency exposed).
// ---------------------------------------------------------------------------
__global__ __launch_bounds__(1024)
void hist1_kernel(const int* __restrict__ dst, int* __restrict__ blockhist,
                  int E, int chunk)
{
    __shared__ int lh[256];
    const int tid = threadIdx.x;
    if (tid < 256) lh[tid] = 0;
    __syncthreads();
    const int beg = blockIdx.x * chunk;
    const int end = min(E, beg + chunk);
    for (int i = beg + tid; i < end; i += 1024)
        atomicAdd(&lh[((unsigned)dst[i]) >> 8], 1);
    __syncthreads();
    if (tid < 256) blockhist[tid * NB1 + blockIdx.x] = lh[tid];
}

// ---------------------------------------------------------------------------
// K3: one-pass exclusive scan of exactly 65536 ints (1024 thr x 64 each).
// ---------------------------------------------------------------------------
__global__ __launch_bounds__(1024, 4)
void scan64k_kernel(const int* __restrict__ in, int* __restrict__ out)
{
    __shared__ int wsum[16];
    const int tid = threadIdx.x, lane = tid & 63, wid = tid >> 6;
    int v[64];
    const int4* p = (const int4*)(in + tid * 64);
#pragma unroll
    for (int i = 0; i < 16; i++) {
        int4 q = p[i];
        v[4 * i] = q.x; v[4 * i + 1] = q.y; v[4 * i + 2] = q.z; v[4 * i + 3] = q.w;
    }
    int tot = 0;
#pragma unroll
    for (int i = 0; i < 64; i++) { int t = v[i]; v[i] = tot; tot += t; }
    int s = tot;
#pragma unroll
    for (int d = 1; d < 64; d <<= 1) {
        int t = __shfl_up(s, d);
        if (lane >= d) s += t;
    }
    if (lane == 63) wsum[wid] = s;
    __syncthreads();
    if (wid == 0 && lane < 16) {
        int w = wsum[lane];
#pragma unroll
        for (int d = 1; d < 16; d <<= 1) {
            int t = __shfl_up(w, d);
            if (lane >= d) w += t;
        }
        wsum[lane] = w;
    }
    __syncthreads();
    const int base = (wid ? wsum[wid - 1] : 0) + (s - tot);
    int4* o = (int4*)(out + tid * 64);
#pragma unroll
    for (int i = 0; i < 16; i++)
        o[i] = make_int4(base + v[4 * i], base + v[4 * i + 1],
                         base + v[4 * i + 2], base + v[4 * i + 3]);
}

// ---------------------------------------------------------------------------
// K4: coarse scatter. 1024 threads (occupancy, as K2). Packs
// (dst low byte)<<16 | src (src < 2^16). No global atomics.
// ---------------------------------------------------------------------------
__global__ __launch_bounds__(1024)
void scatter1_kernel(const int* __restrict__ src, const int* __restrict__ dst,
                     const int* __restrict__ scanned, int* __restrict__ edata,
                     int E, int chunk)
{
    __shared__ int basebin[256];
    __shared__ int cur[256];
    const int tid = threadIdx.x;
    if (tid < 256) {
        basebin[tid] = scanned[tid * NB1 + blockIdx.x];
        cur[tid] = 0;
    }
    __syncthreads();
    const int beg = blockIdx.x * chunk;
    const int end = min(E, beg + chunk);
    for (int i = beg + tid; i < end; i += 1024) {
        int d = dst[i];
        int s = src[i];
        int bin = ((unsigned)d) >> 8;
        int rk = atomicAdd(&cur[bin], 1);
        edata[basebin[bin] + rk] = ((d & 0xFF) << 16) | s;
    }
}

// ---------------------------------------------------------------------------
// K5: fine counting sort within each coarse bucket (256 dst values).
// 1024 threads: only 196 blocks, need waves per block for latency cover.
// ---------------------------------------------------------------------------
__global__ __launch_bounds__(1024)
void bucket_sort_kernel(const int* __restrict__ scanned,
                        const int* __restrict__ edata,
                        int* __restrict__ ssorted,
                        int* __restrict__ cnt, int* __restrict__ offs,
                        int E, int N)
{
    __shared__ int hist[256];
    __shared__ int excl[256];
    const int tid = threadIdx.x;
    const int lane = tid & 63;
    const int cb = blockIdx.x;
    const int base = scanned[cb * NB1];
    const int endp = (cb + 1 < 256) ? scanned[(cb + 1) * NB1] : E;

    if (tid < 256) hist[tid] = 0;
    __syncthreads();
    for (int i = base + tid; i < endp; i += 1024)
        atomicAdd(&hist[((unsigned)edata[i]) >> 16], 1);
    __syncthreads();

    if (tid < 64) {
        int v0 = hist[lane * 4], v1 = hist[lane * 4 + 1];
        int v2 = hist[lane * 4 + 2], v3 = hist[lane * 4 + 3];
        int ts = v0 + v1 + v2 + v3;
        int s = ts;
#pragma unroll
        for (int d = 1; d < 64; d <<= 1) {
            int t = __shfl_up(s, d);
            if (lane >= d) s += t;
        }
        int e = s - ts;
        excl[lane * 4] = e;
        excl[lane * 4 + 1] = e + v0;
        excl[lane * 4 + 2] = e + v0 + v1;
        excl[lane * 4 + 3] = e + v0 + v1 + v2;
    }
    __syncthreads();

    if (tid < 256) {
        int d = cb * 256 + tid;
        if (d < N) {
            cnt[d] = hist[tid];
            offs[d] = base + excl[tid];
        }
    }
    __syncthreads();

    for (int i = base + tid; i < endp; i += 1024) {
        int pack = edata[i];
        int low = ((unsigned)pack) >> 16;
        int rk = atomicAdd(&excl[low], 1);
        ssorted[base + rk] = pack & 0xFFFF;
    }
}

// ---------------------------------------------------------------------------
// K6: per-dst-node online-softmax aggregation. One wave per node; lane = f.
// 16 independent chunk accumulators (deg~16: all gathers in flight).
// ---------------------------------------------------------------------------
__global__ __launch_bounds__(256)
void aggregate_kernel(const unsigned short* __restrict__ hb,
                      const float* __restrict__ sdst,
                      const float* __restrict__ ssrc,
                      const int* __restrict__ offs,
                      const int* __restrict__ cnt,
                      const int* __restrict__ ssorted,
                      float* __restrict__ out, int N)
{
    __shared__ float w_sh[4][64];
    __shared__ int s_sh[4][64];
    const int lane = threadIdx.x & 63;
    const int wid = threadIdx.x >> 6;
    const int d = blockIdx.x * 4 + wid;
    if (d >= N) return;

    const int off = offs[d];
    const int deg = cnt[d];
    const float sdd = sdst[d];
    float M = -INFINITY, S = 0.f, res = 0.f;

    for (int cb = 0; cb < deg; cb += 64) {
        int ce = min(64, deg - cb);
        float score = -INFINITY;
        int s = 0;
        if (lane < ce) {
            s = ssorted[off + cb + lane];
            float sc = sdd + ssrc[s];
            score = sc > 0.f ? sc : NEG_SLOPE * sc;
        }
        float mc = score;
#pragma unroll
        for (int dd = 32; dd > 0; dd >>= 1)
            mc = fmaxf(mc, __shfl_xor(mc, dd));
        float newM = fmaxf(M, mc);
        float scale = __expf(M - newM);
        float w = (lane < ce) ? __expf(score - newM) : 0.f;
        w_sh[wid][lane] = w;
        s_sh[wid][lane] = s;
        float csum = w;
#pragma unroll
        for (int dd = 32; dd > 0; dd >>= 1)
            csum += __shfl_xor(csum, dd);
        S = S * scale + csum;
        __builtin_amdgcn_wave_barrier();
        float c[16];
#pragma unroll
        for (int i = 0; i < 16; i++) c[i] = 0.f;
        int e = 0;
        for (; e + 16 <= ce; e += 16) {
#pragma unroll
            for (int i = 0; i < 16; i++)
                c[i] = fmaf(w_sh[wid][e + i],
                            bf2f(hb[(size_t)s_sh[wid][e + i] * F_OUT + lane]),
                            c[i]);
        }
        for (; e < ce; e++)
            c[e & 15] = fmaf(w_sh[wid][e],
                             bf2f(hb[(size_t)s_sh[wid][e] * F_OUT + lane]),
                             c[e & 15]);
        float t = 0.f;
#pragma unroll
        for (int i = 0; i < 16; i++) t += c[i];
        res = res * scale + t;
        __builtin_amdgcn_wave_barrier();
        M = newM;
    }

    float hf = bf2f(hb[(size_t)d * F_OUT + lane]);
    float r = (S > 0.f) ? (hf - res / S) : hf;
    out[(size_t)d * F_OUT + lane] = r > 0.f ? r : 0.f;
}

// ---------------------------------------------------------------------------
extern "C" void kernel_launch(void* const* d_in, const int* in_sizes, int n_in,
                              void* d_out, int out_size, void* d_ws,
                              size_t ws_size, hipStream_t stream)
{
    const float* x  = (const float*)d_in[0];
    const float* W1 = (const float*)d_in[1];
    const float* W2 = (const float*)d_in[2];
    const float* a  = (const float*)d_in[3];
    const int* src  = (const int*)d_in[4];
    const int* dst  = (const int*)d_in[5];
    const int N = in_sizes[0] / F_IN;   // 50000
    const int E = in_sizes[4];          // 800000

    float* ws         = (float*)d_ws;
    float* sdst       = ws;                              // N
    float* ssrc       = sdst + N;                        // N
    float* w1t        = ssrc + N;                        // 16384
    float* w2t        = w1t + F_IN * F_OUT;              // 4096
    unsigned short* hb = (unsigned short*)(w2t + F_OUT * F_OUT);  // N*64 u16
    int*   cnt        = (int*)(hb + (size_t)N * F_OUT);  // N
    int*   offs       = cnt + N;                         // N
    int*   blockhist  = offs + N;                        // 256*NB1
    int*   scanned    = blockhist + 256 * NB1;           // 256*NB1
    int*   edata      = scanned + 256 * NB1;             // E
    int*   ssorted    = edata + E;                       // E

    const int chunk = (E + NB1 - 1) / NB1;
    const int nbc = (N + 255) >> 8;

    prep_w_kernel<<<(F_IN * F_OUT + 255) / 256, 256, 0, stream>>>(W1, W2, w1t, w2t);
    mlp_kernel<<<(N + 63) / 64, 256, 0, stream>>>(x, w1t, w2t, a, hb, sdst, ssrc, N);
    hist1_kernel<<<NB1, 1024, 0, stream>>>(dst, blockhist, E, chunk);
    scan64k_kernel<<<1, 1024, 0, stream>>>(blockhist, scanned);
    scatter1_kernel<<<NB1, 1024, 0, stream>>>(src, dst, scanned, edata, E, chunk);
    bucket_sort_kernel<<<nbc, 1024, 0, stream>>>(scanned, edata, ssorted, cnt, offs, E, N);
    aggregate_kernel<<<(N + 3) / 4, 256, 0, stream>>>(hb, sdst, ssrc, offs, cnt,
                                                      ssorted, (float*)d_out, N);
}

// Round 8
// 191.804 us; speedup vs baseline: 1.2039x; 1.2039x over previous
//
#include <hip/hip_runtime.h>
#include <math.h>

#define F_IN 256
#define F_OUT 64
#define NEG_SLOPE 0.01f
#define NB1 256   // coarse-pass blocks

typedef unsigned short ushort8_t __attribute__((ext_vector_type(8)));

__device__ inline unsigned short f2bf(float f) {   // RNE
    unsigned u = __float_as_uint(f);
    u += 0x7FFF + ((u >> 16) & 1);
    return (unsigned short)(u >> 16);
}
__device__ inline float bf2f(unsigned short u) {
    return __uint_as_float(((unsigned)u) << 16);
}

// ---------------------------------------------------------------------------
// K0: transpose W1 (64x256 -> k-major 256x64) and W2 (64x64 -> j-major).
// ---------------------------------------------------------------------------
__global__ void prep_w_kernel(const float* __restrict__ W1,
                              const float* __restrict__ W2,
                              float* __restrict__ w1t,
                              float* __restrict__ w2t)
{
    int idx = blockIdx.x * blockDim.x + threadIdx.x;
    if (idx < F_IN * F_OUT) {
        int k = idx >> 6, f = idx & 63;
        w1t[idx] = W1[f * F_IN + k];
    }
    if (idx < F_OUT * F_OUT) {
        int j = idx >> 6, f = idx & 63;
        w2t[idx] = W2[f * F_OUT + j];
    }
}

// ---------------------------------------------------------------------------
// K1: fused MLP (unchanged from R7). Block = 64 nodes x 4 feature-quarters.
// All 16 dwordx4 loads upfront, pinned with sched_barrier(0).
// ---------------------------------------------------------------------------
__global__ __launch_bounds__(256, 3)
void mlp_kernel(const float* __restrict__ x,
                const float* __restrict__ w1t,
                const float* __restrict__ w2t,
                const float* __restrict__ a,
                unsigned short* __restrict__ hb,
                float* __restrict__ sdst,
                float* __restrict__ ssrc, int N)
{
    __shared__ float xt[64 * 65];   // xt[k][node] per chunk; reused as zh/h
    __shared__ float sred[8][64];
    const int tid = threadIdx.x;
    const int lane = tid & 63;
    const int wq = __builtin_amdgcn_readfirstlane(tid >> 6);
    const int node0 = blockIdx.x * 64;

    const int r = tid >> 2, g = tid & 3;
    const int gnode = min(node0 + r, N - 1);
    const float* __restrict__ xsrc = x + (size_t)gnode * F_IN + g * 16;

    float4 v[16];
#pragma unroll
    for (int c = 0; c < 16; c++)
        v[c] = *(const float4*)(xsrc + (c >> 2) * 64 + (c & 3) * 4);
    __builtin_amdgcn_sched_barrier(0);   // pin: do not sink loads

    float acc[16];
#pragma unroll
    for (int f = 0; f < 16; f++) acc[f] = 0.f;

#pragma unroll
    for (int kc = 0; kc < 4; kc++) {
        __syncthreads();
#pragma unroll
        for (int i = 0; i < 4; i++) {
            int k = g * 16 + i * 4;
            float4 vi = v[kc * 4 + i];
            xt[(k + 0) * 65 + r] = vi.x;
            xt[(k + 1) * 65 + r] = vi.y;
            xt[(k + 2) * 65 + r] = vi.z;
            xt[(k + 3) * 65 + r] = vi.w;
        }
        __syncthreads();

        const float* __restrict__ wbase = w1t + (kc * 64) * F_OUT + wq * 16;
#pragma unroll 8
        for (int k = 0; k < 64; k++) {
            float xk = xt[k * 65 + lane];
            const float4* __restrict__ wrow = (const float4*)(wbase + k * F_OUT);
#pragma unroll
            for (int fq = 0; fq < 4; fq++) {
                float4 w = wrow[fq];
                acc[4 * fq + 0] = fmaf(xk, w.x, acc[4 * fq + 0]);
                acc[4 * fq + 1] = fmaf(xk, w.y, acc[4 * fq + 1]);
                acc[4 * fq + 2] = fmaf(xk, w.z, acc[4 * fq + 2]);
                acc[4 * fq + 3] = fmaf(xk, w.w, acc[4 * fq + 3]);
            }
        }
    }
    __syncthreads();

#pragma unroll
    for (int f = 0; f < 16; f++)
        xt[lane * 65 + wq * 16 + f] = fmaxf(acc[f], 0.f);
    __syncthreads();

    float hacc[16];
#pragma unroll
    for (int f = 0; f < 16; f++) hacc[f] = 0.f;
    const float* __restrict__ w2p = w2t + wq * 16;
#pragma unroll 8
    for (int j = 0; j < F_OUT; j++) {
        float zj = xt[lane * 65 + j];
        const float4* __restrict__ wrow = (const float4*)(w2p + j * F_OUT);
#pragma unroll
        for (int fq = 0; fq < 4; fq++) {
            float4 w = wrow[fq];
            hacc[4 * fq + 0] = fmaf(zj, w.x, hacc[4 * fq + 0]);
            hacc[4 * fq + 1] = fmaf(zj, w.y, hacc[4 * fq + 1]);
            hacc[4 * fq + 2] = fmaf(zj, w.z, hacc[4 * fq + 2]);
            hacc[4 * fq + 3] = fmaf(zj, w.w, hacc[4 * fq + 3]);
        }
    }
    __syncthreads();

    float sd = 0.f, ss = 0.f;
#pragma unroll
    for (int f = 0; f < 16; f++) {
        float hf = fmaxf(hacc[f], 0.f);
        xt[lane * 65 + wq * 16 + f] = hf;
        sd = fmaf(hf, a[wq * 16 + f], sd);
        ss = fmaf(hf, a[F_OUT + wq * 16 + f], ss);
    }
    sred[wq][lane] = sd;
    sred[4 + wq][lane] = ss;
    __syncthreads();

    if (tid < 64) {
        int node = node0 + lane;
        if (node < N) {
            sdst[node] = sred[0][lane] + sred[1][lane] + sred[2][lane] + sred[3][lane];
            ssrc[node] = sred[4][lane] + sred[5][lane] + sred[6][lane] + sred[7][lane];
        }
    }
#pragma unroll
    for (int i = 0; i < 2; i++) {
        int idx = tid + 256 * i;
        int nn = idx >> 3;
        int c0 = (idx & 7) * 8;
        if (node0 + nn < N) {
            ushort8_t vv;
#pragma unroll
            for (int c = 0; c < 8; c++) vv[c] = f2bf(xt[nn * 65 + c0 + c]);
            *(ushort8_t*)(hb + (size_t)(node0 + nn) * F_OUT + c0) = vv;
        }
    }
}

// ---------------------------------------------------------------------------
// K2: coarse histogram of dst>>8 (unchanged from R7).
// ---------------------------------------------------------------------------
__global__ __launch_bounds__(1024)
void hist1_kernel(const int* __restrict__ dst, int* __restrict__ blockhist,
                  int E, int chunk)
{
    __shared__ int lh[256];
    const int tid = threadIdx.x;
    if (tid < 256) lh[tid] = 0;
    __syncthreads();
    const int beg = blockIdx.x * chunk;
    const int end = min(E, beg + chunk);
    for (int i = beg + tid; i < end; i += 1024)
        atomicAdd(&lh[((unsigned)dst[i]) >> 8], 1);
    __syncthreads();
    if (tid < 256) blockhist[tid * NB1 + blockIdx.x] = lh[tid];
}

// ---------------------------------------------------------------------------
// K3: one-pass exclusive scan of exactly 65536 ints (unchanged).
// ---------------------------------------------------------------------------
__global__ __launch_bounds__(1024, 4)
void scan64k_kernel(const int* __restrict__ in, int* __restrict__ out)
{
    __shared__ int wsum[16];
    const int tid = threadIdx.x, lane = tid & 63, wid = tid >> 6;
    int v[64];
    const int4* p = (const int4*)(in + tid * 64);
#pragma unroll
    for (int i = 0; i < 16; i++) {
        int4 q = p[i];
        v[4 * i] = q.x; v[4 * i + 1] = q.y; v[4 * i + 2] = q.z; v[4 * i + 3] = q.w;
    }
    int tot = 0;
#pragma unroll
    for (int i = 0; i < 64; i++) { int t = v[i]; v[i] = tot; tot += t; }
    int s = tot;
#pragma unroll
    for (int d = 1; d < 64; d <<= 1) {
        int t = __shfl_up(s, d);
        if (lane >= d) s += t;
    }
    if (lane == 63) wsum[wid] = s;
    __syncthreads();
    if (wid == 0 && lane < 16) {
        int w = wsum[lane];
#pragma unroll
        for (int d = 1; d < 16; d <<= 1) {
            int t = __shfl_up(w, d);
            if (lane >= d) w += t;
        }
        wsum[lane] = w;
    }
    __syncthreads();
    const int base = (wid ? wsum[wid - 1] : 0) + (s - tot);
    int4* o = (int4*)(out + tid * 64);
#pragma unroll
    for (int i = 0; i < 16; i++)
        o[i] = make_int4(base + v[4 * i], base + v[4 * i + 1],
                         base + v[4 * i + 2], base + v[4 * i + 3]);
}

// ---------------------------------------------------------------------------
// K4: coarse scatter (unchanged from R7).
// ---------------------------------------------------------------------------
__global__ __launch_bounds__(1024)
void scatter1_kernel(const int* __restrict__ src, const int* __restrict__ dst,
                     const int* __restrict__ scanned, int* __restrict__ edata,
                     int E, int chunk)
{
    __shared__ int basebin[256];
    __shared__ int cur[256];
    const int tid = threadIdx.x;
    if (tid < 256) {
        basebin[tid] = scanned[tid * NB1 + blockIdx.x];
        cur[tid] = 0;
    }
    __syncthreads();
    const int beg = blockIdx.x * chunk;
    const int end = min(E, beg + chunk);
    for (int i = beg + tid; i < end; i += 1024) {
        int d = dst[i];
        int s = src[i];
        int bin = ((unsigned)d) >> 8;
        int rk = atomicAdd(&cur[bin], 1);
        edata[basebin[bin] + rk] = ((d & 0xFF) << 16) | s;
    }
}

// ---------------------------------------------------------------------------
// K5: fine counting sort within each coarse bucket (unchanged from R7).
// ---------------------------------------------------------------------------
__global__ __launch_bounds__(1024)
void bucket_sort_kernel(const int* __restrict__ scanned,
                        const int* __restrict__ edata,
                        int* __restrict__ ssorted,
                        int* __restrict__ cnt, int* __restrict__ offs,
                        int E, int N)
{
    __shared__ int hist[256];
    __shared__ int excl[256];
    const int tid = threadIdx.x;
    const int lane = tid & 63;
    const int cb = blockIdx.x;
    const int base = scanned[cb * NB1];
    const int endp = (cb + 1 < 256) ? scanned[(cb + 1) * NB1] : E;

    if (tid < 256) hist[tid] = 0;
    __syncthreads();
    for (int i = base + tid; i < endp; i += 1024)
        atomicAdd(&hist[((unsigned)edata[i]) >> 16], 1);
    __syncthreads();

    if (tid < 64) {
        int v0 = hist[lane * 4], v1 = hist[lane * 4 + 1];
        int v2 = hist[lane * 4 + 2], v3 = hist[lane * 4 + 3];
        int ts = v0 + v1 + v2 + v3;
        int s = ts;
#pragma unroll
        for (int d = 1; d < 64; d <<= 1) {
            int t = __shfl_up(s, d);
            if (lane >= d) s += t;
        }
        int e = s - ts;
        excl[lane * 4] = e;
        excl[lane * 4 + 1] = e + v0;
        excl[lane * 4 + 2] = e + v0 + v1;
        excl[lane * 4 + 3] = e + v0 + v1 + v2;
    }
    __syncthreads();

    if (tid < 256) {
        int d = cb * 256 + tid;
        if (d < N) {
            cnt[d] = hist[tid];
            offs[d] = base + excl[tid];
        }
    }
    __syncthreads();

    for (int i = base + tid; i < endp; i += 1024) {
        int pack = edata[i];
        int low = ((unsigned)pack) >> 16;
        int rk = atomicAdd(&excl[low], 1);
        ssorted[base + rk] = pack & 0xFFFF;
    }
}

// ---------------------------------------------------------------------------
// K6: per-dst-node online-softmax aggregation. One wave per node; lane = f.
// R7 lesson: dynamic index c[e&15] forced the acc array out of registers
// (select-chain/scratch emulation, 72us @ VALUBusy 68%). Fix: (1) w_sh is
// already 0 for padded lanes -> run the gather loop to ce rounded up to 8,
// ALL indices static, c[8] stays in VGPRs; (2) edge index is wave-uniform ->
// readfirstlane moves row-base calc to SALU; (3) w+s packed in one float2
// -> single ds_read_b64 per edge.
// ---------------------------------------------------------------------------
__global__ __launch_bounds__(256)
void aggregate_kernel(const unsigned short* __restrict__ hb,
                      const float* __restrict__ sdst,
                      const float* __restrict__ ssrc,
                      const int* __restrict__ offs,
                      const int* __restrict__ cnt,
                      const int* __restrict__ ssorted,
                      float* __restrict__ out, int N)
{
    __shared__ float2 ws_sh[4][64];
    const int lane = threadIdx.x & 63;
    const int wid = threadIdx.x >> 6;
    const int d = blockIdx.x * 4 + wid;
    if (d >= N) return;

    const int off = offs[d];
    const int deg = cnt[d];
    const float sdd = sdst[d];
    float M = -INFINITY, S = 0.f, res = 0.f;

    for (int cb = 0; cb < deg; cb += 64) {
        int ce = min(64, deg - cb);
        float score = -INFINITY;
        int s = 0;
        if (lane < ce) {
            s = ssorted[off + cb + lane];
            float sc = sdd + ssrc[s];
            score = sc > 0.f ? sc : NEG_SLOPE * sc;
        }
        float mc = score;
#pragma unroll
        for (int dd = 32; dd > 0; dd >>= 1)
            mc = fmaxf(mc, __shfl_xor(mc, dd));
        float newM = fmaxf(M, mc);
        float scale = __expf(M - newM);
        float w = (lane < ce) ? __expf(score - newM) : 0.f;
        ws_sh[wid][lane] = make_float2(w, __int_as_float(s));  // w=0 pads
        float csum = w;
#pragma unroll
        for (int dd = 32; dd > 0; dd >>= 1)
            csum += __shfl_xor(csum, dd);
        S = S * scale + csum;
        __builtin_amdgcn_wave_barrier();

        float c[8];
#pragma unroll
        for (int i = 0; i < 8; i++) c[i] = 0.f;
        const int ceo = (ce + 7) & ~7;     // padded: w==0, s==0 beyond ce
        for (int e = 0; e < ceo; e += 8) {
#pragma unroll
            for (int i = 0; i < 8; i++) {
                float2 t = ws_sh[wid][e + i];
                int se = __builtin_amdgcn_readfirstlane(__float_as_int(t.y));
                c[i] = fmaf(t.x, bf2f(hb[((unsigned)se << 6) + lane]), c[i]);
            }
        }
        float t = ((c[0] + c[1]) + (c[2] + c[3])) + ((c[4] + c[5]) + (c[6] + c[7]));
        res = res * scale + t;
        __builtin_amdgcn_wave_barrier();
        M = newM;
    }

    float hf = bf2f(hb[((unsigned)d << 6) + lane]);
    float r = (S > 0.f) ? (hf - res / S) : hf;
    out[(size_t)d * F_OUT + lane] = r > 0.f ? r : 0.f;
}

// ---------------------------------------------------------------------------
extern "C" void kernel_launch(void* const* d_in, const int* in_sizes, int n_in,
                              void* d_out, int out_size, void* d_ws,
                              size_t ws_size, hipStream_t stream)
{
    const float* x  = (const float*)d_in[0];
    const float* W1 = (const float*)d_in[1];
    const float* W2 = (const float*)d_in[2];
    const float* a  = (const float*)d_in[3];
    const int* src  = (const int*)d_in[4];
    const int* dst  = (const int*)d_in[5];
    const int N = in_sizes[0] / F_IN;   // 50000
    const int E = in_sizes[4];          // 800000

    float* ws         = (float*)d_ws;
    float* sdst       = ws;                              // N
    float* ssrc       = sdst + N;                        // N
    float* w1t        = ssrc + N;                        // 16384
    float* w2t        = w1t + F_IN * F_OUT;              // 4096
    unsigned short* hb = (unsigned short*)(w2t + F_OUT * F_OUT);  // N*64 u16
    int*   cnt        = (int*)(hb + (size_t)N * F_OUT);  // N
    int*   offs       = cnt + N;                         // N
    int*   blockhist  = offs + N;                        // 256*NB1
    int*   scanned    = blockhist + 256 * NB1;           // 256*NB1
    int*   edata      = scanned + 256 * NB1;             // E
    int*   ssorted    = edata + E;                       // E

    const int chunk = (E + NB1 - 1) / NB1;
    const int nbc = (N + 255) >> 8;

    prep_w_kernel<<<(F_IN * F_OUT + 255) / 256, 256, 0, stream>>>(W1, W2, w1t, w2t);
    mlp_kernel<<<(N + 63) / 64, 256, 0, stream>>>(x, w1t, w2t, a, hb, sdst, ssrc, N);
    hist1_kernel<<<NB1, 1024, 0, stream>>>(dst, blockhist, E, chunk);
    scan64k_kernel<<<1, 1024, 0, stream>>>(blockhist, scanned);
    scatter1_kernel<<<NB1, 1024, 0, stream>>>(src, dst, scanned, edata, E, chunk);
    bucket_sort_kernel<<<nbc, 1024, 0, stream>>>(scanned, edata, ssorted, cnt, offs, E, N);
    aggregate_kernel<<<(N + 3) / 4, 256, 0, stream>>>(hb, sdst, ssrc, offs, cnt,
                                                      ssorted, (float*)d_out, N);
}

// Round 9
// 174.281 us; speedup vs baseline: 1.3250x; 1.1005x over previous
//
#include <hip/hip_runtime.h>
#include <math.h>

#define F_IN 256
#define F_OUT 64
#define NEG_SLOPE 0.01f
#define CAP 8192          // fixed capacity per coarse bucket (mean 4096, sigma 64)
#define NB2 256           // scatter_fused blocks

typedef unsigned short ushort8_t __attribute__((ext_vector_type(8)));
typedef __bf16 bf16x8 __attribute__((ext_vector_type(8)));
typedef float f32x16 __attribute__((ext_vector_type(16)));

__device__ inline unsigned short f2bf(float f) {   // RNE
    unsigned u = __float_as_uint(f);
    u += 0x7FFF + ((u >> 16) & 1);
    return (unsigned short)(u >> 16);
}
__device__ inline float bf2f(unsigned short u) {
    return __uint_as_float(((unsigned)u) << 16);
}
// fp32 -> bf16 hi + bf16 lo (hi+lo ~ 2^-17 rel accurate)
__device__ inline void splitbf(float x, unsigned short& hi, unsigned short& lo) {
    hi = f2bf(x);
    lo = f2bf(x - bf2f(hi));
}
__device__ inline bf16x8 asbf8(ushort8_t u) {
    union { ushort8_t u; bf16x8 b; } c; c.u = u; return c.b;
}

// ---------------------------------------------------------------------------
// K0: build MFMA B-fragments of W1, W2 as bf16 hi/lo pairs.
// 32x32x16 B layout: B[k][n]: n = lane&31, k = (lane>>5)*8 + j.
// w1frag[((gks*2+nt)*64 + lane)*8 + j] covers f = nt*32+(lane&31),
// k = gks*16 + (lane>>5)*8 + j  (gks 0..15). w2frag same with K=64 (ks 0..3).
// ---------------------------------------------------------------------------
__global__ __launch_bounds__(256)
void prep_frag_kernel(const float* __restrict__ W1, const float* __restrict__ W2,
                      unsigned short* __restrict__ w1fh, unsigned short* __restrict__ w1fl,
                      unsigned short* __restrict__ w2fh, unsigned short* __restrict__ w2fl)
{
    int idx = blockIdx.x * blockDim.x + threadIdx.x;   // 0..16383
    int jj = idx & 7, l = (idx >> 3) & 63, t = idx >> 9;
    {
        int nt = t & 1, gks = t >> 1;
        int f = nt * 32 + (l & 31);
        int k = gks * 16 + (l >> 5) * 8 + jj;
        unsigned short hi, lo;
        splitbf(W1[f * F_IN + k], hi, lo);
        w1fh[idx] = hi; w1fl[idx] = lo;
    }
    if (idx < 4096) {
        int nt = t & 1, ks = t >> 1;   // t 0..7
        int f = nt * 32 + (l & 31);
        int j = ks * 16 + (l >> 5) * 8 + jj;
        unsigned short hi, lo;
        splitbf(W2[f * F_OUT + j], hi, lo);
        w2fh[idx] = hi; w2fl[idx] = lo;
    }
}

// ---------------------------------------------------------------------------
// K1: fused MLP via MFMA (R5-R8 lesson: VALU GEMM is capped ~44us by weight
// s_load latency + 32cyc/k FMA floor; matrix pipe does it in ~2us).
// fp32 inputs split to bf16 hi+lo; 3 MFMAs (hh, hl, lh) ~ fp32 precision so
// scores stay softmax-safe. Block = 64 nodes; wave (mt,nt) owns a 32x32 tile.
// x staged to LDS pre-split (row stride 134 ushort = 67 dw, odd -> <=2-way).
// ---------------------------------------------------------------------------
__global__ __launch_bounds__(256, 4)
void mlp_kernel(const float* __restrict__ x,
                const unsigned short* __restrict__ w1fh,
                const unsigned short* __restrict__ w1fl,
                const unsigned short* __restrict__ w2fh,
                const unsigned short* __restrict__ w2fl,
                const float* __restrict__ a,
                unsigned short* __restrict__ hb,
                float* __restrict__ sdst,
                float* __restrict__ ssrc, int N)
{
    __shared__ __align__(16) char smem[34304];
    __shared__ float sred[8][64];
    unsigned short* xh  = (unsigned short*)smem;             // 64 x 134
    unsigned short* xl  = (unsigned short*)(smem + 17152);   // 64 x 134
    unsigned short* zh16 = (unsigned short*)smem;            // 64 x 66 (phase 2)
    unsigned short* zl16 = (unsigned short*)(smem + 8448);   // 64 x 66
    float* zhf = (float*)(smem + 17408);                     // 64 x 65 (phase 3)

    const int tid = threadIdx.x;
    const int lane = tid & 63;
    const int wq = __builtin_amdgcn_readfirstlane(tid >> 6);
    const int mt = wq >> 1, nt = wq & 1;
    const int ml = lane & 31;          // M/N index within 32-tile
    const int q = lane >> 5;           // K-octet selector
    const int node0 = blockIdx.x * 64;

    // staging: thread r=tid>>2 (node), g=tid&3 (32-k group within half)
    const int r = tid >> 2, g = tid & 3;
    const int gnode = min(node0 + r, N - 1);
    const float* __restrict__ xsrc = x + (size_t)gnode * F_IN + g * 32;

    f32x16 acc;
#pragma unroll
    for (int i = 0; i < 16; i++) acc[i] = 0.f;

    float4 v[8];
#pragma unroll
    for (int i = 0; i < 8; i++) v[i] = *(const float4*)(xsrc + i * 4);

#pragma unroll
    for (int half = 0; half < 2; half++) {
        __syncthreads();   // prev half consumed (first: no-op semantics)
#pragma unroll
        for (int i = 0; i < 8; i++) {
            int kidx = r * 134 + g * 32 + i * 4;
            ushort4 hi4, lo4;
            splitbf(v[i].x, hi4.x, lo4.x);
            splitbf(v[i].y, hi4.y, lo4.y);
            splitbf(v[i].z, hi4.z, lo4.z);
            splitbf(v[i].w, hi4.w, lo4.w);
            *(ushort4*)(xh + kidx) = hi4;
            *(ushort4*)(xl + kidx) = lo4;
        }
        __syncthreads();
        if (half == 0) {   // prefetch second half while MFMAs run
#pragma unroll
            for (int i = 0; i < 8; i++)
                v[i] = *(const float4*)(xsrc + 128 + i * 4);
        }
#pragma unroll
        for (int ks = 0; ks < 8; ks++) {
            int gks = half * 8 + ks;
            bf16x8 bh = asbf8(*(const ushort8_t*)(w1fh + (((gks * 2 + nt) * 64) + lane) * 8));
            bf16x8 bl = asbf8(*(const ushort8_t*)(w1fl + (((gks * 2 + nt) * 64) + lane) * 8));
            int aidx = (mt * 32 + ml) * 134 + ks * 16 + q * 8;
            bf16x8 ah = asbf8(*(const ushort8_t*)(xh + aidx));
            bf16x8 al = asbf8(*(const ushort8_t*)(xl + aidx));
            acc = __builtin_amdgcn_mfma_f32_32x32x16_bf16(ah, bh, acc, 0, 0, 0);
            acc = __builtin_amdgcn_mfma_f32_32x32x16_bf16(ah, bl, acc, 0, 0, 0);
            acc = __builtin_amdgcn_mfma_f32_32x32x16_bf16(al, bh, acc, 0, 0, 0);
        }
    }
    __syncthreads();   // all GEMM1 reads done; smem becomes z arrays

    // z = relu(acc), split to bf16 hi/lo in LDS (C layout: col=lane&31,
    // row=(reg&3)+8*(reg>>2)+4*(lane>>5))
#pragma unroll
    for (int reg = 0; reg < 16; reg++) {
        int nd = mt * 32 + (reg & 3) + 8 * (reg >> 2) + 4 * q;
        float z = fmaxf(acc[reg], 0.f);
        unsigned short hi, lo;
        splitbf(z, hi, lo);
        zh16[nd * 66 + nt * 32 + ml] = hi;
        zl16[nd * 66 + nt * 32 + ml] = lo;
    }
    __syncthreads();

    // GEMM2: h = z @ W2^T via 4 ksteps x 3 split-MFMAs
    f32x16 hacc;
#pragma unroll
    for (int i = 0; i < 16; i++) hacc[i] = 0.f;
#pragma unroll
    for (int ks = 0; ks < 4; ks++) {
        bf16x8 bh = asbf8(*(const ushort8_t*)(w2fh + (((ks * 2 + nt) * 64) + lane) * 8));
        bf16x8 bl = asbf8(*(const ushort8_t*)(w2fl + (((ks * 2 + nt) * 64) + lane) * 8));
        int aidx = (mt * 32 + ml) * 66 + ks * 16 + q * 8;
        bf16x8 ah = asbf8(*(const ushort8_t*)(zh16 + aidx));
        bf16x8 al = asbf8(*(const ushort8_t*)(zl16 + aidx));
        hacc = __builtin_amdgcn_mfma_f32_32x32x16_bf16(ah, bh, hacc, 0, 0, 0);
        hacc = __builtin_amdgcn_mfma_f32_32x32x16_bf16(ah, bl, hacc, 0, 0, 0);
        hacc = __builtin_amdgcn_mfma_f32_32x32x16_bf16(al, bh, hacc, 0, 0, 0);
    }
    // h (relu, fp32) to zhf region (disjoint from z arrays -> no barrier yet)
#pragma unroll
    for (int reg = 0; reg < 16; reg++) {
        int nd = mt * 32 + (reg & 3) + 8 * (reg >> 2) + 4 * q;
        zhf[nd * 65 + nt * 32 + ml] = fmaxf(hacc[reg], 0.f);
    }
    __syncthreads();

    // epilogue: scores + bf16 h store (node = lane, feats wq*16..+15)
    float sd = 0.f, ss = 0.f;
#pragma unroll
    for (int f = 0; f < 16; f++) {
        float hf = zhf[lane * 65 + wq * 16 + f];
        sd = fmaf(hf, a[wq * 16 + f], sd);
        ss = fmaf(hf, a[F_OUT + wq * 16 + f], ss);
    }
    sred[wq][lane] = sd;
    sred[4 + wq][lane] = ss;
    __syncthreads();

    if (tid < 64) {
        int node = node0 + lane;
        if (node < N) {
            sdst[node] = sred[0][lane] + sred[1][lane] + sred[2][lane] + sred[3][lane];
            ssrc[node] = sred[4][lane] + sred[5][lane] + sred[6][lane] + sred[7][lane];
        }
    }
#pragma unroll
    for (int i = 0; i < 2; i++) {
        int idx = tid + 256 * i;
        int nn = idx >> 3;
        int c0 = (idx & 7) * 8;
        if (node0 + nn < N) {
            ushort8_t vv;
#pragma unroll
            for (int c = 0; c < 8; c++) vv[c] = f2bf(zhf[nn * 65 + c0 + c]);
            *(ushort8_t*)(hb + (size_t)(node0 + nn) * F_OUT + c0) = vv;
        }
    }
}

// ---------------------------------------------------------------------------
// K2: fused hist+scatter (replaces hist1+scan64k+scatter1). Per-block LDS
// hist of dst>>8, ONE global atomicAdd per (block,bucket) reserves a
// sub-range in the bucket's fixed-CAP region, then LDS-cursor scatter.
// No per-edge global atomics (R2 lesson), no global scan.
// ---------------------------------------------------------------------------
__global__ __launch_bounds__(1024)
void scatter_fused_kernel(const int* __restrict__ src, const int* __restrict__ dst,
                          int* __restrict__ cursor, int* __restrict__ edata,
                          int E, int chunk)
{
    __shared__ int lh[256], lbase[256], lcur[256];
    const int tid = threadIdx.x;
    if (tid < 256) lh[tid] = 0;
    __syncthreads();
    const int beg = blockIdx.x * chunk;
    const int end = min(E, beg + chunk);
    for (int i = beg + tid; i < end; i += 1024)
        atomicAdd(&lh[((unsigned)dst[i]) >> 8], 1);
    __syncthreads();
    if (tid < 256) {
        int c = lh[tid];
        lbase[tid] = c ? atomicAdd(&cursor[tid], c) : 0;
        lcur[tid] = 0;
    }
    __syncthreads();
    for (int i = beg + tid; i < end; i += 1024) {
        int d = dst[i];
        int s = src[i];
        int b = ((unsigned)d) >> 8;
        int rk = atomicAdd(&lcur[b], 1);
        edata[b * CAP + lbase[b] + rk] = ((d & 0xFF) << 16) | s;
    }
}

// ---------------------------------------------------------------------------
// K3: fine counting sort within each coarse bucket (bucket-strided I/O).
// ---------------------------------------------------------------------------
__global__ __launch_bounds__(1024)
void bucket_sort_kernel(const int* __restrict__ cursor,
                        const int* __restrict__ edata,
                        int* __restrict__ ssorted,
                        int* __restrict__ cnt, int* __restrict__ offs, int N)
{
    __shared__ int hist[256];
    __shared__ int excl[256];
    const int tid = threadIdx.x;
    const int lane = tid & 63;
    const int cb = blockIdx.x;
    const int base = cb * CAP;
    const int ecnt = cursor[cb];

    if (tid < 256) hist[tid] = 0;
    __syncthreads();
    for (int i = tid; i < ecnt; i += 1024)
        atomicAdd(&hist[((unsigned)edata[base + i]) >> 16], 1);
    __syncthreads();

    if (tid < 64) {
        int v0 = hist[lane * 4], v1 = hist[lane * 4 + 1];
        int v2 = hist[lane * 4 + 2], v3 = hist[lane * 4 + 3];
        int ts = v0 + v1 + v2 + v3;
        int s = ts;
#pragma unroll
        for (int d = 1; d < 64; d <<= 1) {
            int t = __shfl_up(s, d);
            if (lane >= d) s += t;
        }
        int e = s - ts;
        excl[lane * 4] = e;
        excl[lane * 4 + 1] = e + v0;
        excl[lane * 4 + 2] = e + v0 + v1;
        excl[lane * 4 + 3] = e + v0 + v1 + v2;
    }
    __syncthreads();

    if (tid < 256) {
        int d = cb * 256 + tid;
        if (d < N) {
            cnt[d] = hist[tid];
            offs[d] = base + excl[tid];
        }
    }
    __syncthreads();

    for (int i = tid; i < ecnt; i += 1024) {
        int pack = edata[base + i];
        int low = ((unsigned)pack) >> 16;
        int rk = atomicAdd(&excl[low], 1);
        ssorted[base + rk] = pack & 0xFFFF;
    }
}

// ---------------------------------------------------------------------------
// K4: per-dst-node online-softmax aggregation (unchanged from R8: static
// indices, padded gather, readfirstlane SALU addressing).
// ---------------------------------------------------------------------------
__global__ __launch_bounds__(256)
void aggregate_kernel(const unsigned short* __restrict__ hb,
                      const float* __restrict__ sdst,
                      const float* __restrict__ ssrc,
                      const int* __restrict__ offs,
                      const int* __restrict__ cnt,
                      const int* __restrict__ ssorted,
                      float* __restrict__ out, int N)
{
    __shared__ float2 ws_sh[4][64];
    const int lane = threadIdx.x & 63;
    const int wid = threadIdx.x >> 6;
    const int d = blockIdx.x * 4 + wid;
    if (d >= N) return;

    const int off = offs[d];
    const int deg = cnt[d];
    const float sdd = sdst[d];
    float M = -INFINITY, S = 0.f, res = 0.f;

    for (int cb = 0; cb < deg; cb += 64) {
        int ce = min(64, deg - cb);
        float score = -INFINITY;
        int s = 0;
        if (lane < ce) {
            s = ssorted[off + cb + lane];
            float sc = sdd + ssrc[s];
            score = sc > 0.f ? sc : NEG_SLOPE * sc;
        }
        float mc = score;
#pragma unroll
        for (int dd = 32; dd > 0; dd >>= 1)
            mc = fmaxf(mc, __shfl_xor(mc, dd));
        float newM = fmaxf(M, mc);
        float scale = __expf(M - newM);
        float w = (lane < ce) ? __expf(score - newM) : 0.f;
        ws_sh[wid][lane] = make_float2(w, __int_as_float(s));
        float csum = w;
#pragma unroll
        for (int dd = 32; dd > 0; dd >>= 1)
            csum += __shfl_xor(csum, dd);
        S = S * scale + csum;
        __builtin_amdgcn_wave_barrier();

        float c[8];
#pragma unroll
        for (int i = 0; i < 8; i++) c[i] = 0.f;
        const int ceo = (ce + 7) & ~7;
        for (int e = 0; e < ceo; e += 8) {
#pragma unroll
            for (int i = 0; i < 8; i++) {
                float2 t = ws_sh[wid][e + i];
                int se = __builtin_amdgcn_readfirstlane(__float_as_int(t.y));
                c[i] = fmaf(t.x, bf2f(hb[((unsigned)se << 6) + lane]), c[i]);
            }
        }
        float t = ((c[0] + c[1]) + (c[2] + c[3])) + ((c[4] + c[5]) + (c[6] + c[7]));
        res = res * scale + t;
        __builtin_amdgcn_wave_barrier();
        M = newM;
    }

    float hf = bf2f(hb[((unsigned)d << 6) + lane]);
    float r = (S > 0.f) ? (hf - res / S) : hf;
    out[(size_t)d * F_OUT + lane] = r > 0.f ? r : 0.f;
}

// ---------------------------------------------------------------------------
extern "C" void kernel_launch(void* const* d_in, const int* in_sizes, int n_in,
                              void* d_out, int out_size, void* d_ws,
                              size_t ws_size, hipStream_t stream)
{
    const float* x  = (const float*)d_in[0];
    const float* W1 = (const float*)d_in[1];
    const float* W2 = (const float*)d_in[2];
    const float* a  = (const float*)d_in[3];
    const int* src  = (const int*)d_in[4];
    const int* dst  = (const int*)d_in[5];
    const int N = in_sizes[0] / F_IN;   // 50000
    const int E = in_sizes[4];          // 800000

    float* ws = (float*)d_ws;
    float* sdst = ws;                                   // N
    float* ssrc = sdst + N;                             // N
    unsigned short* w1fh = (unsigned short*)(ssrc + N); // 16384 us = 8192 f
    unsigned short* w1fl = w1fh + 16384;                // 16384 us
    unsigned short* w2fh = w1fl + 16384;                // 4096 us
    unsigned short* w2fl = w2fh + 4096;                 // 4096 us
    unsigned short* hb = w2fl + 4096;                   // N*64 us
    int* cnt    = (int*)(hb + (size_t)N * F_OUT);       // N
    int* offs   = cnt + N;                              // N
    int* cursor = offs + N;                             // 256
    int* edata  = cursor + 256;                         // 196*CAP
    int* ssorted = edata + 196 * CAP;                   // 196*CAP

    const int nbc = (N + 255) >> 8;                     // 196
    const int chunk = (E + NB2 - 1) / NB2;

    hipMemsetAsync(cursor, 0, 256 * sizeof(int), stream);
    prep_frag_kernel<<<64, 256, 0, stream>>>(W1, W2, w1fh, w1fl, w2fh, w2fl);
    mlp_kernel<<<(N + 63) / 64, 256, 0, stream>>>(x, w1fh, w1fl, w2fh, w2fl, a,
                                                  hb, sdst, ssrc, N);
    scatter_fused_kernel<<<NB2, 1024, 0, stream>>>(src, dst, cursor, edata, E, chunk);
    bucket_sort_kernel<<<nbc, 1024, 0, stream>>>(cursor, edata, ssorted, cnt, offs, N);
    aggregate_kernel<<<(N + 3) / 4, 256, 0, stream>>>(hb, sdst, ssrc, offs, cnt,
                                                      ssorted, (float*)d_out, N);
}